// Round 8
// baseline (162.792 us; speedup 1.0000x reference)
//
#include <hip/hip_runtime.h>
#include <math.h>

#define D 2048
#define NROWS 16384
#define BLOCK 256
#define WPB   (BLOCK / 64)     // 4 waves per block
#define GRID  2048             // 8192 waves = max residency (256 CU x 32)
#define TOTW  (GRID * WPB)     // 8192
#define RPW   (NROWS / TOTW)   // 2 rows per wave

__global__ __launch_bounds__(BLOCK) void pal_fused(const float* __restrict__ recon,
                                                   const float* __restrict__ x,
                                                   float* __restrict__ out,
                                                   float* __restrict__ partial,
                                                   unsigned* __restrict__ ticket) {
    const int wave = threadIdx.x >> 6;
    const int lane = threadIdx.x & 63;
    const int gw   = blockIdx.x * WPB + wave;

    float wsum = 0.f;

#pragma unroll 1
    for (int r = 0; r < RPW; ++r) {
        const int row = gw + r * TOTW;
        const float4* a4 = reinterpret_cast<const float4*>(recon + (size_t)row * D);
        const float4* b4 = reinterpret_cast<const float4*>(x     + (size_t)row * D);

        float dot = 0.f, rr = 0.f, xx = 0.f;
#pragma unroll
        for (int j = 0; j < 8; ++j) {
            float4 a = a4[lane + 64 * j];
            float4 b = b4[lane + 64 * j];
            dot += a.x * b.x + a.y * b.y + a.z * b.z + a.w * b.w;
            rr  += a.x * a.x + a.y * a.y + a.z * a.z + a.w * a.w;
            xx  += b.x * b.x + b.y * b.y + b.z * b.z + b.w * b.w;
        }

#pragma unroll
        for (int off = 32; off > 0; off >>= 1) {
            dot += __shfl_down(dot, off, 64);
            rr  += __shfl_down(rr,  off, 64);
            xx  += __shfl_down(xx,  off, 64);
        }

        if (lane == 0) {
            float c = dot / sqrtf(rr * xx);
            c = fminf(1.f, fmaxf(-1.f, c));
            wsum += acosf(c);
        }
    }

    __shared__ float sh[WPB];
    __shared__ int last_flag;
    if (lane == 0) sh[wave] = wsum;
    __syncthreads();

    if (threadIdx.x == 0) {
        float s = 0.f;
#pragma unroll
        for (int w = 0; w < WPB; ++w) s += sh[w];
        // agent-scope atomic store: lands at the device-coherent point,
        // immune to per-XCD L2 non-coherence.
        __hip_atomic_store(&partial[blockIdx.x], s, __ATOMIC_RELEASE,
                           __HIP_MEMORY_SCOPE_AGENT);
        unsigned old = __hip_atomic_fetch_add(ticket, 1u, __ATOMIC_ACQ_REL,
                                              __HIP_MEMORY_SCOPE_AGENT);
        last_flag = (old == GRID - 1u);   // ticket memset to 0 each launch
    }
    __syncthreads();

    if (last_flag) {
        // fixed read order -> bit-deterministic result on every replay
        float s = 0.f;
#pragma unroll
        for (int k = 0; k < GRID / BLOCK; ++k)   // 8 per thread
            s += __hip_atomic_load(&partial[threadIdx.x + k * BLOCK],
                                   __ATOMIC_RELAXED, __HIP_MEMORY_SCOPE_AGENT);
#pragma unroll
        for (int off = 32; off > 0; off >>= 1) s += __shfl_down(s, off, 64);
        __shared__ float sh2[WPB];
        if (lane == 0) sh2[wave] = s;
        __syncthreads();
        if (threadIdx.x == 0) {
            out[0] = (sh2[0] + sh2[1] + sh2[2] + sh2[3]) / (float)NROWS;
        }
    }
}

extern "C" void kernel_launch(void* const* d_in, const int* in_sizes, int n_in,
                              void* d_out, int out_size, void* d_ws, size_t ws_size,
                              hipStream_t stream) {
    const float* recon = (const float*)d_in[0];
    const float* x     = (const float*)d_in[1];
    float* out       = (float*)d_out;
    unsigned* ticket = (unsigned*)d_ws;                    // 4 B at offset 0
    float* partial   = (float*)((char*)d_ws + 256);        // GRID floats, own cache line

    hipMemsetAsync(ticket, 0, sizeof(unsigned), stream);   // async, graph-capturable
    pal_fused<<<GRID, BLOCK, 0, stream>>>(recon, x, out, partial, ticket);
}

// Round 9
// 58.171 us; speedup vs baseline: 2.7985x; 2.7985x over previous
//
#include <hip/hip_runtime.h>
#include <math.h>

#define D 2048
#define NROWS 16384
#define BLOCK 256
#define WPB   (BLOCK / 64)     // 4 waves per block
#define GRID  2048             // 8192 waves = max residency (256 CU x 32)
#define TOTW  (GRID * WPB)     // 8192
#define RPW   (NROWS / TOTW)   // 2 rows per wave

__global__ __launch_bounds__(BLOCK) void pal_fused(const float* __restrict__ recon,
                                                   const float* __restrict__ x,
                                                   float* __restrict__ out,
                                                   float* __restrict__ partial,
                                                   unsigned* __restrict__ ticket) {
    const int wave = threadIdx.x >> 6;
    const int lane = threadIdx.x & 63;
    const int gw   = blockIdx.x * WPB + wave;

    float wsum = 0.f;

#pragma unroll 1
    for (int r = 0; r < RPW; ++r) {
        const int row = gw + r * TOTW;
        const float4* a4 = reinterpret_cast<const float4*>(recon + (size_t)row * D);
        const float4* b4 = reinterpret_cast<const float4*>(x     + (size_t)row * D);

        float dot = 0.f, rr = 0.f, xx = 0.f;
#pragma unroll
        for (int j = 0; j < 8; ++j) {
            float4 a = a4[lane + 64 * j];
            float4 b = b4[lane + 64 * j];
            dot += a.x * b.x + a.y * b.y + a.z * b.z + a.w * b.w;
            rr  += a.x * a.x + a.y * a.y + a.z * a.z + a.w * a.w;
            xx  += b.x * b.x + b.y * b.y + b.z * b.z + b.w * b.w;
        }

#pragma unroll
        for (int off = 32; off > 0; off >>= 1) {
            dot += __shfl_down(dot, off, 64);
            rr  += __shfl_down(rr,  off, 64);
            xx  += __shfl_down(xx,  off, 64);
        }

        if (lane == 0) {
            float c = dot / sqrtf(rr * xx);
            c = fminf(1.f, fmaxf(-1.f, c));
            wsum += acosf(c);
        }
    }

    __shared__ float sh[WPB];
    __shared__ int last_flag;
    if (lane == 0) sh[wave] = wsum;
    __syncthreads();

    if (threadIdx.x == 0) {
        float s = 0.f;
#pragma unroll
        for (int w = 0; w < WPB; ++w) s += sh[w];
        // RELAXED atomic store -> lands at the device-coherent point,
        // NO buffer_wbl2 (that was R8's 6x regression).
        __hip_atomic_store(&partial[blockIdx.x], s, __ATOMIC_RELAXED,
                           __HIP_MEMORY_SCOPE_AGENT);
        // Wait for the store's ack at the coherent point before ticketing:
        // cheap per-wave drain (~1 round trip), no cache maintenance.
        asm volatile("s_waitcnt vmcnt(0)" ::: "memory");
        unsigned old = __hip_atomic_fetch_add(ticket, 1u, __ATOMIC_RELAXED,
                                              __HIP_MEMORY_SCOPE_AGENT);
        last_flag = (old == GRID - 1u);   // ticket memset to 0 each launch
    }
    __syncthreads();

    if (last_flag) {
        // All partials are durable at the coherent point (each block ack'd its
        // store before its ticket add). RELAXED agent atomic loads read the
        // coherent point, bypassing this XCD's stale L2.
        float s = 0.f;
#pragma unroll
        for (int k = 0; k < GRID / BLOCK; ++k)   // 8 per thread, fixed order
            s += __hip_atomic_load(&partial[threadIdx.x + k * BLOCK],
                                   __ATOMIC_RELAXED, __HIP_MEMORY_SCOPE_AGENT);
#pragma unroll
        for (int off = 32; off > 0; off >>= 1) s += __shfl_down(s, off, 64);
        __shared__ float sh2[WPB];
        if (lane == 0) sh2[wave] = s;
        __syncthreads();
        if (threadIdx.x == 0) {
            out[0] = (sh2[0] + sh2[1] + sh2[2] + sh2[3]) / (float)NROWS;
        }
    }
}

extern "C" void kernel_launch(void* const* d_in, const int* in_sizes, int n_in,
                              void* d_out, int out_size, void* d_ws, size_t ws_size,
                              hipStream_t stream) {
    const float* recon = (const float*)d_in[0];
    const float* x     = (const float*)d_in[1];
    float* out       = (float*)d_out;
    unsigned* ticket = (unsigned*)d_ws;                 // 4 B at offset 0
    float* partial   = (float*)((char*)d_ws + 256);     // GRID floats, own line

    hipMemsetAsync(ticket, 0, sizeof(unsigned), stream);
    pal_fused<<<GRID, BLOCK, 0, stream>>>(recon, x, out, partial, ticket);
}

// Round 11
// 46.347 us; speedup vs baseline: 3.5124x; 1.2551x over previous
//
#include <hip/hip_runtime.h>
#include <math.h>

#define D 2048
#define NROWS 16384
#define BLOCK 256
#define WPB   (BLOCK / 64)     // 4 waves per block
#define GRID  2048             // 8192 waves = max residency (256 CU x 32)
#define TOTW  (GRID * WPB)     // 8192
#define RPW   (NROWS / TOTW)   // 2 rows per wave, grid-strided

// Best-known configuration (R6): pure streaming kernel at the delivered-BW
// ceiling (268 MB / ~42.5 us = 6.31 TB/s blended HBM+L3, m13 ceiling 6.29),
// plus one minimal 8 KB reduction dispatch (~3.5 us). Fusion attempts (R8/R9)
// regressed: cross-XCD visibility for the last-block pattern costs more than
// a second dispatch on this harness.

__global__ __launch_bounds__(BLOCK) void pal_row_theta(const float* __restrict__ recon,
                                                       const float* __restrict__ x,
                                                       float* __restrict__ blockPartial) {
    const int wave = threadIdx.x >> 6;
    const int lane = threadIdx.x & 63;
    const int gw   = blockIdx.x * WPB + wave;

    float wsum = 0.f;

#pragma unroll 1
    for (int r = 0; r < RPW; ++r) {
        const int row = gw + r * TOTW;
        const float4* a4 = reinterpret_cast<const float4*>(recon + (size_t)row * D);
        const float4* b4 = reinterpret_cast<const float4*>(x     + (size_t)row * D);

        float dot = 0.f, rr = 0.f, xx = 0.f;
#pragma unroll
        for (int j = 0; j < 8; ++j) {
            float4 a = a4[lane + 64 * j];
            float4 b = b4[lane + 64 * j];
            dot += a.x * b.x + a.y * b.y + a.z * b.z + a.w * b.w;
            rr  += a.x * a.x + a.y * a.y + a.z * a.z + a.w * a.w;
            xx  += b.x * b.x + b.y * b.y + b.z * b.z + b.w * b.w;
        }

#pragma unroll
        for (int off = 32; off > 0; off >>= 1) {
            dot += __shfl_down(dot, off, 64);
            rr  += __shfl_down(rr,  off, 64);
            xx  += __shfl_down(xx,  off, 64);
        }

        if (lane == 0) {
            float c = dot / sqrtf(rr * xx);
            c = fminf(1.f, fmaxf(-1.f, c));
            wsum += acosf(c);
        }
    }

    __shared__ float sh[WPB];
    if (lane == 0) sh[wave] = wsum;
    __syncthreads();
    if (threadIdx.x == 0) {
        float s = 0.f;
#pragma unroll
        for (int w = 0; w < WPB; ++w) s += sh[w];
        blockPartial[blockIdx.x] = s;
    }
}

__global__ __launch_bounds__(256) void pal_mean(const float* __restrict__ blockPartial,
                                                float* __restrict__ out) {
    const float4* p4 = reinterpret_cast<const float4*>(blockPartial);  // 2048 floats
    float4 v0 = p4[threadIdx.x];
    float4 v1 = p4[threadIdx.x + 256];
    float s = v0.x + v0.y + v0.z + v0.w + v1.x + v1.y + v1.z + v1.w;
#pragma unroll
    for (int off = 32; off > 0; off >>= 1) s += __shfl_down(s, off, 64);
    __shared__ float sh[4];
    const int wave = threadIdx.x >> 6;
    const int lane = threadIdx.x & 63;
    if (lane == 0) sh[wave] = s;
    __syncthreads();
    if (threadIdx.x == 0) {
        out[0] = (sh[0] + sh[1] + sh[2] + sh[3]) / (float)NROWS;
    }
}

extern "C" void kernel_launch(void* const* d_in, const int* in_sizes, int n_in,
                              void* d_out, int out_size, void* d_ws, size_t ws_size,
                              hipStream_t stream) {
    const float* recon = (const float*)d_in[0];
    const float* x     = (const float*)d_in[1];
    float* out     = (float*)d_out;
    float* partial = (float*)d_ws;   // GRID floats = 8 KB scratch

    pal_row_theta<<<GRID, BLOCK, 0, stream>>>(recon, x, partial);
    pal_mean<<<1, 256, 0, stream>>>(partial, out);
}